// Round 6
// baseline (1737.705 us; speedup 1.0000x reference)
//
#include <hip/hip_runtime.h>
#include <hip/hip_bf16.h>
#include <math.h>

// GraphCast processor, round 5.
// - All GEMM A-operands maintained as PRE-SPLIT bf16 hi/lo pairs by producers
//   (init/node_agg/ln_silu_split/Wn2-epilogue). GEMM staging = pure
//   global_load_lds width-16, no VALU split, unpadded 32-short LDS rows.
// - P fp32 (consumer node_agg is fp32). u fp32 aliases P[0:N*256]; uh/ul alias
//   P's second half (dead after node_agg).
// - node_agg: 32-lane halves process 2 edges concurrently (8 feats/lane,
//   5-stage interleaved sum/sumsq tree, xor-32 combine) — replaces the R3
//   prefetch that regressed occupancy (VGPR 36->44, occ 51->36).

#define NNODES 40962
#define NEDGES 163848
#define NLAYERS 6

typedef __attribute__((ext_vector_type(8))) short short8;
typedef __attribute__((ext_vector_type(4))) float f32x4;

__device__ __forceinline__ void async_copy16(void* lds, const void* g) {
    __builtin_amdgcn_global_load_lds(
        (const __attribute__((address_space(1))) unsigned int*)g,
        (__attribute__((address_space(3))) unsigned int*)lds, 16, 0, 0);
}

// split a,b (fp32) -> packed hi bf16x2, lo bf16x2 (truncation split; hi+lo ~ 16-bit mantissa)
__device__ __forceinline__ void split2(float a, float b, unsigned int& hi, unsigned int& lo) {
    unsigned int u0 = __float_as_uint(a), u1 = __float_as_uint(b);
    float l0 = a - __uint_as_float(u0 & 0xFFFF0000u);
    float l1 = b - __uint_as_float(u1 & 0xFFFF0000u);
    hi = (u0 >> 16) | (u1 & 0xFFFF0000u);
    lo = (__float_as_uint(l0) >> 16) | (__float_as_uint(l1) & 0xFFFF0000u);
}

// ---------------- weight prep: transpose fp32 [R][C] -> bf16(RNE) [C][R] ----------------
__global__ __launch_bounds__(256) void wprep_kernel(
    const float* __restrict__ src, unsigned short* __restrict__ dst,
    int R, int C, size_t src_lstride, size_t src_hstride, int halves)
{
    __shared__ float t[32][33];
    const int b = blockIdx.z;
    src += (size_t)(b / halves) * src_lstride + (size_t)(b % halves) * src_hstride;
    dst += (size_t)b * R * C;
    const int tx = threadIdx.x & 31, ty = threadIdx.x >> 5;
    const int c0 = blockIdx.x * 32, r0 = blockIdx.y * 32;
    #pragma unroll
    for (int i = 0; i < 4; ++i)
        t[ty + 8 * i][tx] = src[(size_t)(r0 + ty + 8 * i) * C + c0 + tx];
    __syncthreads();
    #pragma unroll
    for (int i = 0; i < 4; ++i) {
        unsigned int u = __float_as_uint(t[tx][ty + 8 * i]);
        unsigned short h = (unsigned short)((u + 0x7FFFu + ((u >> 16) & 1u)) >> 16); // RNE
        dst[(size_t)(c0 + ty + 8 * i) * R + r0 + tx] = h;
    }
}

// ---------------- init: x = mesh (fp32, to d_out) + xh/xl split ----------------
__global__ __launch_bounds__(256) void init_split_kernel(
    const float* __restrict__ mesh, float* __restrict__ x,
    unsigned short* __restrict__ xh, unsigned short* __restrict__ xl, int total4)
{
    int i = blockIdx.x * 256 + threadIdx.x;   // one float4 per thread
    if (i >= total4) return;
    f32x4 v = ((const f32x4*)mesh)[i];
    ((f32x4*)x)[i] = v;
    unsigned int h0, l0, h1, l1;
    split2(v.x, v.y, h0, l0);
    split2(v.z, v.w, h1, l1);
    ((uint2*)xh)[i] = make_uint2(h0, h1);
    ((uint2*)xl)[i] = make_uint2(l0, l1);
}

// ---------------- MFMA GEMM ----------------
// C = (A_hi+A_lo) @ BT^T (+bias) (+resid), A = K-concat(A1,A2) at k=256.
// A sources pre-split bf16 [M,256] ld=256. BT bf16 [Ncols][K].
// Optional split outputs Ch/Cl (bf16 hi/lo of C).
__global__ __launch_bounds__(256) void gemm_mfma(
    const unsigned short* __restrict__ A1h, const unsigned short* __restrict__ A1l,
    const unsigned short* __restrict__ A2h, const unsigned short* __restrict__ A2l,
    const unsigned short* __restrict__ BT,
    const float* __restrict__ bias, const float* __restrict__ resid,
    float* __restrict__ C, unsigned short* __restrict__ Ch, unsigned short* __restrict__ Cl,
    int M, int K, int ldC)
{
    __shared__ __align__(16) short Ah[128 * 32];
    __shared__ __align__(16) short Al[128 * 32];
    __shared__ __align__(16) short Bs[128 * 32];

    const int tid = threadIdx.x;
    const int wave = tid >> 6, lane = tid & 63;
    const int m0 = blockIdx.x * 128, n0 = blockIdx.y * 128;
    const int wm = wave >> 1, wn = wave & 1;
    const int fm = lane & 15, quad = lane >> 4, ko = quad * 8;

    const int r_in = lane >> 2;   // 0..15 (row within 16-row staging chunk)
    const int seg  = lane & 3;    // 0..3  (16B segment within 64B row)

    f32x4 acc[4][4];
    #pragma unroll
    for (int i = 0; i < 4; ++i)
        #pragma unroll
        for (int j = 0; j < 4; ++j)
            acc[i][j] = (f32x4){0.f, 0.f, 0.f, 0.f};

    const int nkt = K >> 5;
    for (int kt = 0; kt < nkt; ++kt) {
        const int k0 = kt << 5;
        const unsigned short *Ahs, *Als; int kb;
        if (A2h != nullptr && k0 >= 256) { Ahs = A2h; Als = A2l; kb = k0 - 256; }
        else                             { Ahs = A1h; Als = A1l; kb = k0; }

        #pragma unroll
        for (int i = 0; i < 2; ++i) {
            const int r = wave * 32 + i * 16 + r_in;        // 0..127
            int gr = m0 + r; if (gr > M - 1) gr = M - 1;    // clamp (masked at store)
            const int lbase = (wave * 32 + i * 16) * 32;    // wave-uniform LDS base
            async_copy16(&Ah[lbase], Ahs + (size_t)gr * 256 + kb + seg * 8);
            async_copy16(&Al[lbase], Als + (size_t)gr * 256 + kb + seg * 8);
            async_copy16(&Bs[lbase], BT + (size_t)(n0 + r) * K + k0 + seg * 8);
        }

        __syncthreads();

        short8 afh[4], afl[4], bf[4];
        #pragma unroll
        for (int i = 0; i < 4; ++i) {
            const int r = wm * 64 + i * 16 + fm;
            afh[i] = *(const short8*)&Ah[r * 32 + ko];
            afl[i] = *(const short8*)&Al[r * 32 + ko];
        }
        #pragma unroll
        for (int j = 0; j < 4; ++j) {
            const int r = wn * 64 + j * 16 + fm;
            bf[j] = *(const short8*)&Bs[r * 32 + ko];
        }
        #pragma unroll
        for (int i = 0; i < 4; ++i)
            #pragma unroll
            for (int j = 0; j < 4; ++j) {
                acc[i][j] = __builtin_amdgcn_mfma_f32_16x16x32_bf16(afl[i], bf[j], acc[i][j], 0, 0, 0);
                acc[i][j] = __builtin_amdgcn_mfma_f32_16x16x32_bf16(afh[i], bf[j], acc[i][j], 0, 0, 0);
            }

        __syncthreads();
    }

    // epilogue: C/D layout col=lane&15, row=quad*4+reg
    #pragma unroll
    for (int j = 0; j < 4; ++j) {
        const int gc = n0 + wn * 64 + j * 16 + fm;
        const float bj = bias ? bias[gc] : 0.f;
        #pragma unroll
        for (int i = 0; i < 4; ++i) {
            #pragma unroll
            for (int r = 0; r < 4; ++r) {
                const int gr = m0 + wm * 64 + i * 16 + quad * 4 + r;
                if (gr < M) {
                    float v = acc[i][j][r] + bj;
                    if (resid) v += resid[(size_t)gr * ldC + gc];
                    C[(size_t)gr * ldC + gc] = v;
                    if (Ch) {
                        unsigned int u = __float_as_uint(v);
                        float lo = v - __uint_as_float(u & 0xFFFF0000u);
                        Ch[(size_t)gr * ldC + gc] = (unsigned short)(u >> 16);
                        Cl[(size_t)gr * ldC + gc] = (unsigned short)(__float_as_uint(lo) >> 16);
                    }
                }
            }
        }
    }
}

// ---------------- CSR build (once per launch) ----------------
__global__ __launch_bounds__(256) void count_kernel(
    const int* __restrict__ dst, int* __restrict__ deg, int E)
{
    int e = blockIdx.x * 256 + threadIdx.x;
    if (e < E) atomicAdd(&deg[dst[e]], 1);
}

__global__ __launch_bounds__(1024) void scan_kernel(
    const int* __restrict__ deg, int* __restrict__ rowptr, int n)
{
    __shared__ int wsum[16];
    __shared__ int carry_s;
    const int tid = threadIdx.x;
    const int lane = tid & 63, wave = tid >> 6;
    if (tid == 0) carry_s = 0;
    __syncthreads();

    for (int base = 0; base < n; base += 1024) {
        int i = base + tid;
        int v = (i < n) ? deg[i] : 0;
        int x = v;
        #pragma unroll
        for (int o = 1; o < 64; o <<= 1) {
            int t = __shfl_up(x, o);
            if (lane >= o) x += t;
        }
        if (lane == 63) wsum[wave] = x;
        __syncthreads();
        if (wave == 0 && lane < 16) {
            int w = wsum[lane];
            #pragma unroll
            for (int o = 1; o < 16; o <<= 1) {
                int t = __shfl_up(w, o);
                if (lane >= o) w += t;
            }
            wsum[lane] = w;
        }
        __syncthreads();
        int wave_off = (wave == 0) ? 0 : wsum[wave - 1];
        int incl = x + wave_off + carry_s;
        if (i < n) rowptr[i] = incl - v;
        __syncthreads();
        if (tid == 0) carry_s += wsum[15];
        __syncthreads();
    }
    if (tid == 0) rowptr[n] = carry_s;
}

__global__ __launch_bounds__(256) void scatter_kernel(
    const int* __restrict__ dst, int* __restrict__ cursor,
    int* __restrict__ esorted, int E)
{
    int e = blockIdx.x * 256 + threadIdx.x;
    if (e < E) {
        int p = atomicAdd(&cursor[dst[e]], 1);
        esorted[p] = e;
    }
}

// ---------------- fused per-node message + aggregate ----------------
// One wave per node; lanes 0-31 process even incident edges, 32-63 odd
// (two gather+reduce chains in flight). 8 feats/lane, 5-stage interleaved
// sum/sumsq tree, xor-32 combine at the end. Writes agg hi/lo bf16.
__global__ __launch_bounds__(256) void node_agg_kernel(
    const float* __restrict__ P,      // [N,512]
    const int* __restrict__ src,
    const float* __restrict__ attr,   // [E,4]
    const float* __restrict__ W3,     // [4,256]
    const float* __restrict__ be, const float* __restrict__ g1, const float* __restrict__ b1,
    const int* __restrict__ rowptr, const int* __restrict__ esorted,
    unsigned short* __restrict__ aggh, unsigned short* __restrict__ aggl, int N)
{
    const int wave = threadIdx.x >> 6;
    const int lane = threadIdx.x & 63;
    const int half = lane >> 5;
    const int l32  = lane & 31;
    const int n = blockIdx.x * 4 + wave;
    if (n >= N) return;
    const int c0 = l32 * 8;

    float p1[8];
    {
        f32x4 a = *(const f32x4*)(P + (size_t)n * 512 + c0);
        f32x4 b = *(const f32x4*)(P + (size_t)n * 512 + c0 + 4);
        p1[0] = a.x; p1[1] = a.y; p1[2] = a.z; p1[3] = a.w;
        p1[4] = b.x; p1[5] = b.y; p1[6] = b.z; p1[7] = b.w;
    }

    float w3v[4][8], bev[8], g1v[8], b1v[8];
    #pragma unroll
    for (int r = 0; r < 4; ++r) {
        f32x4 a = *(const f32x4*)(W3 + r * 256 + c0);
        f32x4 b = *(const f32x4*)(W3 + r * 256 + c0 + 4);
        w3v[r][0] = a.x; w3v[r][1] = a.y; w3v[r][2] = a.z; w3v[r][3] = a.w;
        w3v[r][4] = b.x; w3v[r][5] = b.y; w3v[r][6] = b.z; w3v[r][7] = b.w;
    }
    {
        f32x4 a, b;
        a = *(const f32x4*)(be + c0); b = *(const f32x4*)(be + c0 + 4);
        bev[0]=a.x; bev[1]=a.y; bev[2]=a.z; bev[3]=a.w; bev[4]=b.x; bev[5]=b.y; bev[6]=b.z; bev[7]=b.w;
        a = *(const f32x4*)(g1 + c0); b = *(const f32x4*)(g1 + c0 + 4);
        g1v[0]=a.x; g1v[1]=a.y; g1v[2]=a.z; g1v[3]=a.w; g1v[4]=b.x; g1v[5]=b.y; g1v[6]=b.z; g1v[7]=b.w;
        a = *(const f32x4*)(b1 + c0); b = *(const f32x4*)(b1 + c0 + 4);
        b1v[0]=a.x; b1v[1]=a.y; b1v[2]=a.z; b1v[3]=a.w; b1v[4]=b.x; b1v[5]=b.y; b1v[6]=b.z; b1v[7]=b.w;
    }

    float acc[8] = {0.f, 0.f, 0.f, 0.f, 0.f, 0.f, 0.f, 0.f};
    const int beg = rowptr[n];
    const int end = rowptr[n + 1];

    for (int i = beg + half; i < end; i += 2) {
        const int e = esorted[i];
        const int s = src[e];
        f32x4 pa = *(const f32x4*)(P + (size_t)s * 512 + 256 + c0);
        f32x4 pb = *(const f32x4*)(P + (size_t)s * 512 + 256 + c0 + 4);
        f32x4 av = *(const f32x4*)(attr + (size_t)e * 4);
        float ps[8] = {pa.x, pa.y, pa.z, pa.w, pb.x, pb.y, pb.z, pb.w};

        float h[8];
        #pragma unroll
        for (int j = 0; j < 8; ++j) {
            float w = av.x * w3v[0][j] + av.y * w3v[1][j] + av.z * w3v[2][j] + av.w * w3v[3][j];
            h[j] = p1[j] + ps[j] + w + bev[j];
        }

        float s_ = ((h[0] + h[1]) + (h[2] + h[3])) + ((h[4] + h[5]) + (h[6] + h[7]));
        float q_ = ((h[0]*h[0] + h[1]*h[1]) + (h[2]*h[2] + h[3]*h[3]))
                 + ((h[4]*h[4] + h[5]*h[5]) + (h[6]*h[6] + h[7]*h[7]));
        #pragma unroll
        for (int o = 16; o > 0; o >>= 1) {   // 5 stages within the 32-lane half
            s_ += __shfl_xor(s_, o);
            q_ += __shfl_xor(q_, o);
        }
        const float mean = s_ * (1.0f / 256.0f);
        const float var  = q_ * (1.0f / 256.0f) - mean * mean;
        const float rstd = rsqrtf(var + 1e-5f);

        #pragma unroll
        for (int j = 0; j < 8; ++j) {
            float y = (h[j] - mean) * rstd * g1v[j] + b1v[j];
            acc[j] += y / (1.0f + __expf(-y));
        }
    }

    // combine the two halves (feature c0+j lives in lane l32 of BOTH halves)
    #pragma unroll
    for (int j = 0; j < 8; ++j) acc[j] += __shfl_xor(acc[j], 32);

    if (half == 0) {
        unsigned int h0, l0, h1, l1, h2, l2, h3, l3;
        split2(acc[0], acc[1], h0, l0);
        split2(acc[2], acc[3], h1, l1);
        split2(acc[4], acc[5], h2, l2);
        split2(acc[6], acc[7], h3, l3);
        *(uint4*)(aggh + (size_t)n * 256 + c0) = make_uint4(h0, h1, h2, h3);
        *(uint4*)(aggl + (size_t)n * 256 + c0) = make_uint4(l0, l1, l2, l3);
    }
}

// ---------------- LN + SiLU + hi/lo split of u [N,256] ----------------
__global__ __launch_bounds__(256) void ln_silu_split_kernel(
    const float* __restrict__ u, const float* __restrict__ g, const float* __restrict__ b,
    unsigned short* __restrict__ uh, unsigned short* __restrict__ ul, int N)
{
    const int wave = threadIdx.x >> 6;
    const int lane = threadIdx.x & 63;
    const int r = blockIdx.x * 4 + wave;
    if (r >= N) return;

    float4 hv = *(const float4*)(u + (size_t)r * 256 + lane * 4);
    float h[4] = {hv.x, hv.y, hv.z, hv.w};

    float s_ = (h[0] + h[1]) + (h[2] + h[3]);
    float q_ = (h[0]*h[0] + h[1]*h[1]) + (h[2]*h[2] + h[3]*h[3]);
    #pragma unroll
    for (int o = 32; o > 0; o >>= 1) {
        s_ += __shfl_xor(s_, o);
        q_ += __shfl_xor(q_, o);
    }
    const float mean = s_ * (1.0f / 256.0f);
    const float var  = q_ * (1.0f / 256.0f) - mean * mean;
    const float rstd = rsqrtf(var + 1e-5f);

    #pragma unroll
    for (int i = 0; i < 4; ++i) {
        const int c = lane * 4 + i;
        float y = (h[i] - mean) * rstd * g[c] + b[c];
        h[i] = y / (1.0f + __expf(-y));
    }
    unsigned int h0, l0, h1, l1;
    split2(h[0], h[1], h0, l0);
    split2(h[2], h[3], h1, l1);
    ((uint2*)(uh + (size_t)r * 256))[lane] = make_uint2(h0, h1);
    ((uint2*)(ul + (size_t)r * 256))[lane] = make_uint2(l0, l1);
}

extern "C" void kernel_launch(void* const* d_in, const int* in_sizes, int n_in,
                              void* d_out, int out_size, void* d_ws, size_t ws_size,
                              hipStream_t stream) {
    const float* mesh   = (const float*)d_in[0];
    const int*   eidx   = (const int*)  d_in[1];
    const float* eattr  = (const float*)d_in[2];
    const float* We_w   = (const float*)d_in[3];
    const float* We_b   = (const float*)d_in[4];
    const float* ln1_g  = (const float*)d_in[5];
    const float* ln1_b  = (const float*)d_in[6];
    const float* Wn1_w  = (const float*)d_in[7];
    const float* Wn1_b  = (const float*)d_in[8];
    const float* ln2_g  = (const float*)d_in[9];
    const float* ln2_b  = (const float*)d_in[10];
    const float* Wn2_w  = (const float*)d_in[11];
    const float* Wn2_b  = (const float*)d_in[12];

    const int N = NNODES, E = NEDGES;

    float* x = (float*)d_out;                   // [N,256] fp32 master latents

    float* P = (float*)d_ws;                    // [N,512] fp32
    float* u = P;                               // [N,256] fp32, aliases P (dead after node_agg)
    unsigned short* uh = (unsigned short*)(P + (size_t)N * 256);   // aliases P 2nd half
    unsigned short* ul = uh + (size_t)N * 256;

    unsigned short* xh   = (unsigned short*)(P + (size_t)N * 512);
    unsigned short* xl   = xh + (size_t)N * 256;
    unsigned short* aggh = xl + (size_t)N * 256;
    unsigned short* aggl = aggh + (size_t)N * 256;
    int* deg     = (int*)(aggl + (size_t)N * 256);
    int* rowptr  = deg + N;
    int* cursor  = rowptr + (N + 1);
    int* esorted = cursor + N;                  // E
    uintptr_t wp = (uintptr_t)(esorted + E);
    wp = (wp + 63) & ~(uintptr_t)63;
    unsigned short* BTe  = (unsigned short*)wp;            // [6][512][256]
    unsigned short* BTn1 = BTe  + (size_t)6 * 512 * 256;   // [6][256][512]
    unsigned short* BTn2 = BTn1 + (size_t)6 * 256 * 512;   // [6][256][256]

    const int* src = eidx;
    const int* dst = eidx + E;

    // init: x = mesh + split to xh/xl
    const int total4 = N * 64;   // N*256/4
    init_split_kernel<<<(total4 + 255) / 256, 256, 0, stream>>>(mesh, x, xh, xl, total4);

    // weight prep
    wprep_kernel<<<dim3(8, 8, 12), 256, 0, stream>>>(
        We_w, BTe, 256, 256, (size_t)516 * 256, (size_t)256 * 256, 2);
    wprep_kernel<<<dim3(8, 16, 6), 256, 0, stream>>>(
        Wn1_w, BTn1, 512, 256, (size_t)512 * 256, 0, 1);
    wprep_kernel<<<dim3(8, 8, 6), 256, 0, stream>>>(
        Wn2_w, BTn2, 256, 256, (size_t)256 * 256, 0, 1);

    // CSR build
    hipMemsetAsync(deg, 0, (size_t)N * sizeof(int), stream);
    count_kernel<<<(E + 255) / 256, 256, 0, stream>>>(dst, deg, E);
    scan_kernel<<<1, 1024, 0, stream>>>(deg, rowptr, N);
    hipMemcpyAsync(cursor, rowptr, (size_t)N * sizeof(int),
                   hipMemcpyDeviceToDevice, stream);
    scatter_kernel<<<(E + 255) / 256, 256, 0, stream>>>(dst, cursor, esorted, E);

    const int mblocks = (N + 127) / 128;   // 321
    const int node_blocks = (N + 3) / 4;   // 10241

    for (int l = 0; l < NLAYERS; ++l) {
        const float* W3  = We_w + (size_t)l * 516 * 256 + (size_t)512 * 256;
        const float* be  = We_b  + (size_t)l * 256;
        const float* g1  = ln1_g + (size_t)l * 256;
        const float* b1  = ln1_b + (size_t)l * 256;
        const float* bn1 = Wn1_b + (size_t)l * 256;
        const float* g2  = ln2_g + (size_t)l * 256;
        const float* b2  = ln2_b + (size_t)l * 256;
        const float* bn2 = Wn2_b + (size_t)l * 256;
        const unsigned short* bte  = BTe  + (size_t)l * 512 * 256;
        const unsigned short* btn1 = BTn1 + (size_t)l * 256 * 512;
        const unsigned short* btn2 = BTn2 + (size_t)l * 256 * 256;

        // P = x @ [W1|W2] -> [N,512] fp32
        gemm_mfma<<<dim3(mblocks, 4), 256, 0, stream>>>(
            xh, xl, nullptr, nullptr, bte, nullptr, nullptr,
            P, nullptr, nullptr, N, 256, 512);
        // agg (hi/lo) from CSR walk over P
        node_agg_kernel<<<node_blocks, 256, 0, stream>>>(
            P, src, eattr, W3, be, g1, b1, rowptr, esorted, aggh, aggl, N);
        // u = [x | agg] @ Wn1 + bn1 -> fp32 (into P[0:N*256], P dead)
        gemm_mfma<<<dim3(mblocks, 2), 256, 0, stream>>>(
            xh, xl, aggh, aggl, btn1, bn1, nullptr,
            u, nullptr, nullptr, N, 512, 256);
        // uh/ul = split(silu(LN(u)))
        ln_silu_split_kernel<<<node_blocks, 256, 0, stream>>>(u, g2, b2, uh, ul, N);
        // x = x + silu(LN(u)) @ Wn2 + bn2 ; also refresh xh/xl
        gemm_mfma<<<dim3(mblocks, 2), 256, 0, stream>>>(
            uh, ul, nullptr, nullptr, btn2, bn2, x,
            x, xh, xl, N, 256, 256);
    }
}

// Round 7
// 1594.316 us; speedup vs baseline: 1.0899x; 1.0899x over previous
//
#include <hip/hip_runtime.h>
#include <hip/hip_bf16.h>
#include <math.h>

// GraphCast processor, round 7: consolidation of measured-best pieces.
// - GEMM = R3 version (fp32 A, hi/lo bf16 split in staging — the split VALU work
//   fills staging latency for free; R6 proved removing it gains nothing).
// - node_agg = R6 half-wave version (2 edges in flight per wave), fp32 agg out.
// - LN2 via row_stats + fusion into Wn2 A-staging (R3 scheme).
// R5/R6's producer-split plumbing removed (+150us of extra traffic).

#define NNODES 40962
#define NEDGES 163848
#define NLAYERS 6

typedef __attribute__((ext_vector_type(8))) short short8;
typedef __attribute__((ext_vector_type(4))) float f32x4;

__device__ __forceinline__ void async_copy16(void* lds, const void* g) {
    __builtin_amdgcn_global_load_lds(
        (const __attribute__((address_space(1))) unsigned int*)g,
        (__attribute__((address_space(3))) unsigned int*)lds, 16, 0, 0);
}

// ---------------- weight prep: transpose fp32 [R][C] -> bf16(RNE) [C][R] ----------------
__global__ __launch_bounds__(256) void wprep_kernel(
    const float* __restrict__ src, unsigned short* __restrict__ dst,
    int R, int C, size_t src_lstride, size_t src_hstride, int halves)
{
    __shared__ float t[32][33];
    const int b = blockIdx.z;
    src += (size_t)(b / halves) * src_lstride + (size_t)(b % halves) * src_hstride;
    dst += (size_t)b * R * C;
    const int tx = threadIdx.x & 31, ty = threadIdx.x >> 5;
    const int c0 = blockIdx.x * 32, r0 = blockIdx.y * 32;
    #pragma unroll
    for (int i = 0; i < 4; ++i)
        t[ty + 8 * i][tx] = src[(size_t)(r0 + ty + 8 * i) * C + c0 + tx];
    __syncthreads();
    #pragma unroll
    for (int i = 0; i < 4; ++i) {
        unsigned int u = __float_as_uint(t[tx][ty + 8 * i]);
        unsigned short h = (unsigned short)((u + 0x7FFFu + ((u >> 16) & 1u)) >> 16); // RNE
        dst[(size_t)(c0 + ty + 8 * i) * R + r0 + tx] = h;
    }
}

// ---------------- MFMA GEMM (R3 version) ----------------
// C = (A1 K-concat A2) @ B (+bias) (+resid). Optional fused LN+SiLU on A rows:
// if lnstats != null, A := silu((A - mean)*rstd*lng[c] + lnb[c]) applied in staging.
__global__ __launch_bounds__(256) void gemm_mfma(
    const float* __restrict__ A1, const float* __restrict__ A2,
    const unsigned short* __restrict__ BT,
    const float* __restrict__ bias, const float* __restrict__ resid,
    const float2* __restrict__ lnstats, const float* __restrict__ lng,
    const float* __restrict__ lnb,
    float* __restrict__ C, int M, int K, int ldC)
{
    __shared__ __align__(16) short Ah[128 * 40];
    __shared__ __align__(16) short Al[128 * 40];
    __shared__ __align__(16) short Bs[128 * 32];

    const int tid = threadIdx.x;
    const int wave = tid >> 6;
    const int lane = tid & 63;
    const int m0 = blockIdx.x * 128;
    const int n0 = blockIdx.y * 128;
    const int wm = wave >> 1;
    const int wn = wave & 1;
    const int fm = lane & 15;
    const int quad = lane >> 4;
    const int ko = quad * 8;

    const int arow = tid >> 1;
    const int akh = (tid & 1) * 16;
    const int gr_stage = m0 + arow;

    f32x4 acc[4][4];
    #pragma unroll
    for (int i = 0; i < 4; ++i)
        #pragma unroll
        for (int j = 0; j < 4; ++j)
            acc[i][j] = (f32x4){0.f, 0.f, 0.f, 0.f};

    const int nkt = K >> 5;
    for (int kt = 0; kt < nkt; ++kt) {
        const int k0 = kt << 5;
        const float* Asrc; int kb;
        if (A2 != nullptr && k0 >= 256) { Asrc = A2; kb = k0 - 256; }
        else                            { Asrc = A1; kb = k0; }

        // --- B: async global->LDS ---
        {
            const int n_row = wave * 32 + (lane >> 2);
            const char* gbase = (const char*)BT + (((size_t)(n0 + n_row) * K + k0) << 1)
                              + ((lane & 3) << 4);
            char* lbase = (char*)Bs + wave * 2048;
            async_copy16(lbase, gbase);
            const char* gbase2 = gbase + ((size_t)16 * K << 1);
            async_copy16(lbase + 1024, gbase2);
        }

        // --- A: fp32 load (-> optional LN+SiLU) -> hi/lo bf16 split -> LDS ---
        {
            float f[16];
            if (gr_stage < M) {
                const float* ap = Asrc + (size_t)gr_stage * 256 + kb + akh;
                #pragma unroll
                for (int i = 0; i < 4; ++i) {
                    f32x4 v = *(const f32x4*)(ap + 4 * i);
                    f[4 * i + 0] = v.x; f[4 * i + 1] = v.y;
                    f[4 * i + 2] = v.z; f[4 * i + 3] = v.w;
                }
                if (lnstats != nullptr) {
                    const float2 st = lnstats[gr_stage];
                    #pragma unroll
                    for (int i = 0; i < 16; ++i) {
                        const int c = k0 + akh + i;
                        float y = (f[i] - st.x) * st.y * lng[c] + lnb[c];
                        f[i] = y / (1.0f + __expf(-y));
                    }
                }
            } else {
                #pragma unroll
                for (int i = 0; i < 16; ++i) f[i] = 0.f;
            }
            unsigned int hid[8], lod[8];
            #pragma unroll
            for (int i = 0; i < 8; ++i) {
                unsigned int u0 = __float_as_uint(f[2 * i]);
                unsigned int u1 = __float_as_uint(f[2 * i + 1]);
                float l0 = f[2 * i]     - __uint_as_float(u0 & 0xFFFF0000u);
                float l1 = f[2 * i + 1] - __uint_as_float(u1 & 0xFFFF0000u);
                hid[i] = (u0 >> 16) | (u1 & 0xFFFF0000u);
                lod[i] = (__float_as_uint(l0) >> 16) | (__float_as_uint(l1) & 0xFFFF0000u);
            }
            short* ah = &Ah[arow * 40 + akh];
            short* al = &Al[arow * 40 + akh];
            ((uint4*)ah)[0] = make_uint4(hid[0], hid[1], hid[2], hid[3]);
            ((uint4*)ah)[1] = make_uint4(hid[4], hid[5], hid[6], hid[7]);
            ((uint4*)al)[0] = make_uint4(lod[0], lod[1], lod[2], lod[3]);
            ((uint4*)al)[1] = make_uint4(lod[4], lod[5], lod[6], lod[7]);
        }

        __syncthreads();

        short8 afh[4], afl[4], bf[4];
        #pragma unroll
        for (int i = 0; i < 4; ++i) {
            const int r = wm * 64 + i * 16 + fm;
            afh[i] = *(const short8*)&Ah[r * 40 + ko];
            afl[i] = *(const short8*)&Al[r * 40 + ko];
        }
        #pragma unroll
        for (int j = 0; j < 4; ++j) {
            const int r = wn * 64 + j * 16 + fm;
            bf[j] = *(const short8*)&Bs[r * 32 + ko];
        }
        #pragma unroll
        for (int i = 0; i < 4; ++i)
            #pragma unroll
            for (int j = 0; j < 4; ++j) {
                acc[i][j] = __builtin_amdgcn_mfma_f32_16x16x32_bf16(afl[i], bf[j], acc[i][j], 0, 0, 0);
                acc[i][j] = __builtin_amdgcn_mfma_f32_16x16x32_bf16(afh[i], bf[j], acc[i][j], 0, 0, 0);
            }

        __syncthreads();
    }

    #pragma unroll
    for (int j = 0; j < 4; ++j) {
        const int gc = n0 + wn * 64 + j * 16 + fm;
        const float bj = bias ? bias[gc] : 0.f;
        #pragma unroll
        for (int i = 0; i < 4; ++i) {
            #pragma unroll
            for (int r = 0; r < 4; ++r) {
                const int gr = m0 + wm * 64 + i * 16 + quad * 4 + r;
                if (gr < M) {
                    float v = acc[i][j][r] + bj;
                    if (resid) v += resid[(size_t)gr * ldC + gc];
                    C[(size_t)gr * ldC + gc] = v;
                }
            }
        }
    }
}

// ---------------- CSR build (once per launch) ----------------
__global__ __launch_bounds__(256) void count_kernel(
    const int* __restrict__ dst, int* __restrict__ deg, int E)
{
    int e = blockIdx.x * 256 + threadIdx.x;
    if (e < E) atomicAdd(&deg[dst[e]], 1);
}

__global__ __launch_bounds__(1024) void scan_kernel(
    const int* __restrict__ deg, int* __restrict__ rowptr, int n)
{
    __shared__ int wsum[16];
    __shared__ int carry_s;
    const int tid = threadIdx.x;
    const int lane = tid & 63, wave = tid >> 6;
    if (tid == 0) carry_s = 0;
    __syncthreads();

    for (int base = 0; base < n; base += 1024) {
        int i = base + tid;
        int v = (i < n) ? deg[i] : 0;
        int x = v;
        #pragma unroll
        for (int o = 1; o < 64; o <<= 1) {
            int t = __shfl_up(x, o);
            if (lane >= o) x += t;
        }
        if (lane == 63) wsum[wave] = x;
        __syncthreads();
        if (wave == 0 && lane < 16) {
            int w = wsum[lane];
            #pragma unroll
            for (int o = 1; o < 16; o <<= 1) {
                int t = __shfl_up(w, o);
                if (lane >= o) w += t;
            }
            wsum[lane] = w;
        }
        __syncthreads();
        int wave_off = (wave == 0) ? 0 : wsum[wave - 1];
        int incl = x + wave_off + carry_s;
        if (i < n) rowptr[i] = incl - v;
        __syncthreads();
        if (tid == 0) carry_s += wsum[15];
        __syncthreads();
    }
    if (tid == 0) rowptr[n] = carry_s;
}

__global__ __launch_bounds__(256) void scatter_kernel(
    const int* __restrict__ dst, int* __restrict__ cursor,
    int* __restrict__ esorted, int E)
{
    int e = blockIdx.x * 256 + threadIdx.x;
    if (e < E) {
        int p = atomicAdd(&cursor[dst[e]], 1);
        esorted[p] = e;
    }
}

// ---------------- fused per-node message + aggregate (R6 half-wave version) ----------------
// One wave per node; lanes 0-31 process even incident edges, 32-63 odd
// (two gather+reduce chains in flight). 8 feats/lane, 5-stage interleaved
// sum/sumsq tree, xor-32 combine at the end. fp32 agg out.
__global__ __launch_bounds__(256) void node_agg_kernel(
    const float* __restrict__ P,      // [N,512]
    const int* __restrict__ src,
    const float* __restrict__ attr,   // [E,4]
    const float* __restrict__ W3,     // [4,256]
    const float* __restrict__ be, const float* __restrict__ g1, const float* __restrict__ b1,
    const int* __restrict__ rowptr, const int* __restrict__ esorted,
    float* __restrict__ agg, int N)
{
    const int wave = threadIdx.x >> 6;
    const int lane = threadIdx.x & 63;
    const int half = lane >> 5;
    const int l32  = lane & 31;
    const int n = blockIdx.x * 4 + wave;
    if (n >= N) return;
    const int c0 = l32 * 8;

    float p1[8];
    {
        f32x4 a = *(const f32x4*)(P + (size_t)n * 512 + c0);
        f32x4 b = *(const f32x4*)(P + (size_t)n * 512 + c0 + 4);
        p1[0] = a.x; p1[1] = a.y; p1[2] = a.z; p1[3] = a.w;
        p1[4] = b.x; p1[5] = b.y; p1[6] = b.z; p1[7] = b.w;
    }

    float w3v[4][8], bev[8], g1v[8], b1v[8];
    #pragma unroll
    for (int r = 0; r < 4; ++r) {
        f32x4 a = *(const f32x4*)(W3 + r * 256 + c0);
        f32x4 b = *(const f32x4*)(W3 + r * 256 + c0 + 4);
        w3v[r][0] = a.x; w3v[r][1] = a.y; w3v[r][2] = a.z; w3v[r][3] = a.w;
        w3v[r][4] = b.x; w3v[r][5] = b.y; w3v[r][6] = b.z; w3v[r][7] = b.w;
    }
    {
        f32x4 a, b;
        a = *(const f32x4*)(be + c0); b = *(const f32x4*)(be + c0 + 4);
        bev[0]=a.x; bev[1]=a.y; bev[2]=a.z; bev[3]=a.w; bev[4]=b.x; bev[5]=b.y; bev[6]=b.z; bev[7]=b.w;
        a = *(const f32x4*)(g1 + c0); b = *(const f32x4*)(g1 + c0 + 4);
        g1v[0]=a.x; g1v[1]=a.y; g1v[2]=a.z; g1v[3]=a.w; g1v[4]=b.x; g1v[5]=b.y; g1v[6]=b.z; g1v[7]=b.w;
        a = *(const f32x4*)(b1 + c0); b = *(const f32x4*)(b1 + c0 + 4);
        b1v[0]=a.x; b1v[1]=a.y; b1v[2]=a.z; b1v[3]=a.w; b1v[4]=b.x; b1v[5]=b.y; b1v[6]=b.z; b1v[7]=b.w;
    }

    float acc[8] = {0.f, 0.f, 0.f, 0.f, 0.f, 0.f, 0.f, 0.f};
    const int beg = rowptr[n];
    const int end = rowptr[n + 1];

    for (int i = beg + half; i < end; i += 2) {
        const int e = esorted[i];
        const int s = src[e];
        f32x4 pa = *(const f32x4*)(P + (size_t)s * 512 + 256 + c0);
        f32x4 pb = *(const f32x4*)(P + (size_t)s * 512 + 256 + c0 + 4);
        f32x4 av = *(const f32x4*)(attr + (size_t)e * 4);
        float ps[8] = {pa.x, pa.y, pa.z, pa.w, pb.x, pb.y, pb.z, pb.w};

        float h[8];
        #pragma unroll
        for (int j = 0; j < 8; ++j) {
            float w = av.x * w3v[0][j] + av.y * w3v[1][j] + av.z * w3v[2][j] + av.w * w3v[3][j];
            h[j] = p1[j] + ps[j] + w + bev[j];
        }

        float s_ = ((h[0] + h[1]) + (h[2] + h[3])) + ((h[4] + h[5]) + (h[6] + h[7]));
        float q_ = ((h[0]*h[0] + h[1]*h[1]) + (h[2]*h[2] + h[3]*h[3]))
                 + ((h[4]*h[4] + h[5]*h[5]) + (h[6]*h[6] + h[7]*h[7]));
        #pragma unroll
        for (int o = 16; o > 0; o >>= 1) {   // 5 stages within the 32-lane half
            s_ += __shfl_xor(s_, o);
            q_ += __shfl_xor(q_, o);
        }
        const float mean = s_ * (1.0f / 256.0f);
        const float var  = q_ * (1.0f / 256.0f) - mean * mean;
        const float rstd = rsqrtf(var + 1e-5f);

        #pragma unroll
        for (int j = 0; j < 8; ++j) {
            float y = (h[j] - mean) * rstd * g1v[j] + b1v[j];
            acc[j] += y / (1.0f + __expf(-y));
        }
    }

    // combine the two halves (feature c0+j lives in lane l32 of BOTH halves)
    #pragma unroll
    for (int j = 0; j < 8; ++j) acc[j] += __shfl_xor(acc[j], 32);

    if (half == 0) {
        *(f32x4*)(agg + (size_t)n * 256 + c0)     = (f32x4){acc[0], acc[1], acc[2], acc[3]};
        *(f32x4*)(agg + (size_t)n * 256 + c0 + 4) = (f32x4){acc[4], acc[5], acc[6], acc[7]};
    }
}

// Per-row mean/rstd of u [N,256] -> stats[N]. One wave per row.
__global__ __launch_bounds__(256) void row_stats_kernel(
    const float* __restrict__ u, float2* __restrict__ stats, int N)
{
    const int wave = threadIdx.x >> 6;
    const int lane = threadIdx.x & 63;
    const int r = blockIdx.x * 4 + wave;
    if (r >= N) return;

    float4 hv = *(const float4*)(u + (size_t)r * 256 + lane * 4);
    float s_ = (hv.x + hv.y) + (hv.z + hv.w);
    float q_ = (hv.x * hv.x + hv.y * hv.y) + (hv.z * hv.z + hv.w * hv.w);
    #pragma unroll
    for (int o = 32; o > 0; o >>= 1) {
        s_ += __shfl_xor(s_, o);
        q_ += __shfl_xor(q_, o);
    }
    if (lane == 0) {
        const float mean = s_ * (1.0f / 256.0f);
        const float var  = q_ * (1.0f / 256.0f) - mean * mean;
        stats[r] = make_float2(mean, rsqrtf(var + 1e-5f));
    }
}

extern "C" void kernel_launch(void* const* d_in, const int* in_sizes, int n_in,
                              void* d_out, int out_size, void* d_ws, size_t ws_size,
                              hipStream_t stream) {
    const float* mesh   = (const float*)d_in[0];
    const int*   eidx   = (const int*)  d_in[1];
    const float* eattr  = (const float*)d_in[2];
    const float* We_w   = (const float*)d_in[3];
    const float* We_b   = (const float*)d_in[4];
    const float* ln1_g  = (const float*)d_in[5];
    const float* ln1_b  = (const float*)d_in[6];
    const float* Wn1_w  = (const float*)d_in[7];
    const float* Wn1_b  = (const float*)d_in[8];
    const float* ln2_g  = (const float*)d_in[9];
    const float* ln2_b  = (const float*)d_in[10];
    const float* Wn2_w  = (const float*)d_in[11];
    const float* Wn2_b  = (const float*)d_in[12];

    const int N = NNODES, E = NEDGES;

    float* x   = (float*)d_out;                 // [N,256]
    float* P   = (float*)d_ws;                  // [N,512]
    float* u   = P;                             // [N,256] aliases P
    float* agg = P + (size_t)N * 512;           // [N,256]
    int*   deg     = (int*)(agg + (size_t)N * 256);
    int*   rowptr  = deg + N;
    int*   cursor  = rowptr + (N + 1);
    int*   esorted = cursor + N;                // E
    uintptr_t wp = (uintptr_t)(esorted + E);
    wp = (wp + 63) & ~(uintptr_t)63;
    unsigned short* BTe  = (unsigned short*)wp;            // [6][512][256]
    unsigned short* BTn1 = BTe  + (size_t)6 * 512 * 256;   // [6][256][512]
    unsigned short* BTn2 = BTn1 + (size_t)6 * 256 * 512;   // [6][256][256]
    float2* stats = (float2*)(BTn2 + (size_t)6 * 256 * 256);  // [N]

    const int* src = eidx;
    const int* dst = eidx + E;

    hipMemcpyAsync(x, mesh, (size_t)N * 256 * sizeof(float),
                   hipMemcpyDeviceToDevice, stream);

    // ---- weight prep ----
    wprep_kernel<<<dim3(8, 8, 12), 256, 0, stream>>>(
        We_w, BTe, 256, 256, (size_t)516 * 256, (size_t)256 * 256, 2);
    wprep_kernel<<<dim3(8, 16, 6), 256, 0, stream>>>(
        Wn1_w, BTn1, 512, 256, (size_t)512 * 256, 0, 1);
    wprep_kernel<<<dim3(8, 8, 6), 256, 0, stream>>>(
        Wn2_w, BTn2, 256, 256, (size_t)256 * 256, 0, 1);

    // ---- CSR build ----
    hipMemsetAsync(deg, 0, (size_t)N * sizeof(int), stream);
    count_kernel<<<(E + 255) / 256, 256, 0, stream>>>(dst, deg, E);
    scan_kernel<<<1, 1024, 0, stream>>>(deg, rowptr, N);
    hipMemcpyAsync(cursor, rowptr, (size_t)N * sizeof(int),
                   hipMemcpyDeviceToDevice, stream);
    scatter_kernel<<<(E + 255) / 256, 256, 0, stream>>>(dst, cursor, esorted, E);

    const int mblocks = (N + 127) / 128;
    const int node_blocks = (N + 3) / 4;

    for (int l = 0; l < NLAYERS; ++l) {
        const float* W3  = We_w + (size_t)l * 516 * 256 + (size_t)512 * 256;
        const float* be  = We_b  + (size_t)l * 256;
        const float* g1  = ln1_g + (size_t)l * 256;
        const float* b1  = ln1_b + (size_t)l * 256;
        const float* bn1 = Wn1_b + (size_t)l * 256;
        const float* g2  = ln2_g + (size_t)l * 256;
        const float* b2  = ln2_b + (size_t)l * 256;
        const float* bn2 = Wn2_b + (size_t)l * 256;
        const unsigned short* bte  = BTe  + (size_t)l * 512 * 256;
        const unsigned short* btn1 = BTn1 + (size_t)l * 256 * 512;
        const unsigned short* btn2 = BTn2 + (size_t)l * 256 * 256;

        // P = x @ [W1|W2]  -> [N,512]
        gemm_mfma<<<dim3(mblocks, 4), 256, 0, stream>>>(
            x, nullptr, bte, nullptr, nullptr, nullptr, nullptr, nullptr,
            P, N, 256, 512);
        // agg
        node_agg_kernel<<<node_blocks, 256, 0, stream>>>(
            P, src, eattr, W3, be, g1, b1, rowptr, esorted, agg, N);
        // u = [x | agg] @ Wn1 + bn1
        gemm_mfma<<<dim3(mblocks, 2), 256, 0, stream>>>(
            x, agg, btn1, bn1, nullptr, nullptr, nullptr, nullptr,
            u, N, 512, 256);
        // stats of u rows
        row_stats_kernel<<<node_blocks, 256, 0, stream>>>(u, stats, N);
        // x = x + silu(LN(u)) @ Wn2 + bn2   (LN+SiLU fused into A-staging)
        gemm_mfma<<<dim3(mblocks, 2), 256, 0, stream>>>(
            u, nullptr, btn2, bn2, x, stats, g2, b2,
            x, N, 256, 256);
    }
}